// Round 1
// baseline (562.508 us; speedup 1.0000x reference)
//
#include <hip/hip_runtime.h>

#define D 128

// ---------------------------------------------------------------- degree init
__global__ __launch_bounds__(256) void k_deg_init(int* __restrict__ deg, int n) {
    int i = blockIdx.x * 256 + threadIdx.x;
    if (i < n) deg[i] = 1;  // self-loop
}

// ---------------------------------------------------------------- degree count
__global__ __launch_bounds__(256) void k_count(const int* __restrict__ col, int* __restrict__ deg, int E) {
    int e = blockIdx.x * 256 + threadIdx.x;
    if (e < E) atomicAdd(&deg[col[e]], 1);
}

// ------------------------------------------- exclusive scan of in-degree (CSR offsets) + dinv
__global__ __launch_bounds__(1024) void k_scan(const int* __restrict__ deg, int* __restrict__ offsets,
                                               int* __restrict__ cursor, float* __restrict__ dinv, int n) {
    __shared__ int partial[1024];
    int t = threadIdx.x;
    int chunk = (n + 1023) >> 10;
    int beg = t * chunk;
    int end = min(beg + chunk, n);
    int s = 0;
    for (int i = beg; i < end; ++i) s += deg[i] - 1;
    partial[t] = s;
    __syncthreads();
    for (int off = 1; off < 1024; off <<= 1) {
        int tmp = (t >= off) ? partial[t - off] : 0;
        __syncthreads();
        partial[t] += tmp;
        __syncthreads();
    }
    int base = (t == 0) ? 0 : partial[t - 1];
    for (int i = beg; i < end; ++i) {
        offsets[i] = base;
        cursor[i] = base;
        base += deg[i] - 1;
        dinv[i] = rsqrtf((float)deg[i]);
    }
    if (t == 1023) offsets[n] = partial[1023];
}

// ---------------------------------------------------------------- CSR fill (counting sort by dst)
__global__ __launch_bounds__(256) void k_fill(const int* __restrict__ row, const int* __restrict__ col,
                                              int* __restrict__ cursor, int* __restrict__ csr, int E) {
    int e = blockIdx.x * 256 + threadIdx.x;
    if (e < E) {
        int d = col[e];
        int p = atomicAdd(&cursor[d], 1);
        csr[p] = row[e];
    }
}

// ---------------------------------------------------------------- out[r,:] = dinv[r] * (in[r,:] @ W)
// 64 rows/block, 256 threads, thread = 8 rows x 4 cols microtile. W + x-tile in LDS.
__global__ __launch_bounds__(256) void k_gemm(const float* __restrict__ in, const float* __restrict__ W,
                                              const float* __restrict__ dinv, float* __restrict__ out, int n) {
    __shared__ float Ws[D * D];      // 64 KB
    __shared__ float Xs[64 * D];     // 32 KB
    int t = threadIdx.x;
    const float4* W4 = (const float4*)W;
    float4* Ws4 = (float4*)Ws;
#pragma unroll
    for (int i = 0; i < 16; ++i) Ws4[t + i * 256] = W4[t + i * 256];
    int row0 = blockIdx.x * 64;
    const float4* X4 = (const float4*)in;
    float4* Xs4 = (float4*)Xs;
#pragma unroll
    for (int i = 0; i < 8; ++i) {
        int idx = t + i * 256;                  // 0..2047
        int r = row0 + (idx >> 5);
        Xs4[idx] = (r < n) ? X4[(size_t)r * 32 + (idx & 31)] : make_float4(0.f, 0.f, 0.f, 0.f);
    }
    __syncthreads();
    int ty = t >> 5, tx = t & 31;
    int rbase = ty * 8;
    int c0 = tx * 4;
    float4 acc[8];
#pragma unroll
    for (int i = 0; i < 8; ++i) acc[i] = make_float4(0.f, 0.f, 0.f, 0.f);
    for (int k = 0; k < D; k += 4) {
        float4 w0 = *(const float4*)&Ws[(k + 0) * D + c0];
        float4 w1 = *(const float4*)&Ws[(k + 1) * D + c0];
        float4 w2 = *(const float4*)&Ws[(k + 2) * D + c0];
        float4 w3 = *(const float4*)&Ws[(k + 3) * D + c0];
#pragma unroll
        for (int i = 0; i < 8; ++i) {
            float4 xv = *(const float4*)&Xs[(rbase + i) * D + k];
            acc[i].x += xv.x * w0.x + xv.y * w1.x + xv.z * w2.x + xv.w * w3.x;
            acc[i].y += xv.x * w0.y + xv.y * w1.y + xv.z * w2.y + xv.w * w3.y;
            acc[i].z += xv.x * w0.z + xv.y * w1.z + xv.z * w2.z + xv.w * w3.z;
            acc[i].w += xv.x * w0.w + xv.y * w1.w + xv.z * w2.w + xv.w * w3.w;
        }
    }
#pragma unroll
    for (int i = 0; i < 8; ++i) {
        int r = row0 + rbase + i;
        if (r < n) {
            float s = dinv[r];
            float4 v = acc[i];
            v.x *= s; v.y *= s; v.z *= s; v.w *= s;
            *(float4*)&out[(size_t)r * D + c0] = v;
        }
    }
}

// ---------------------------------------------------------------- aggregation: one wave per node
// out[i,:] = relu(dinv[i]*(hp[i,:] + sum_{j in CSR[i]} hp[j,:]) + bias)
__global__ __launch_bounds__(256) void k_agg(const float* __restrict__ hp, const int* __restrict__ offs,
                                             const int* __restrict__ src, const float* __restrict__ dinv,
                                             const float* __restrict__ bias, float* __restrict__ out, int n) {
    int wid = (blockIdx.x * 256 + threadIdx.x) >> 6;
    int lane = threadIdx.x & 63;
    if (wid >= n) return;
    const float2* hp2 = (const float2*)hp;
    float2 acc = hp2[(size_t)wid * 64 + lane];   // self-loop contribution
    int beg = offs[wid], end = offs[wid + 1];
    int e = beg;
    for (; e + 4 <= end; e += 4) {
        int s0 = src[e], s1 = src[e + 1], s2 = src[e + 2], s3 = src[e + 3];
        float2 v0 = hp2[(size_t)s0 * 64 + lane];
        float2 v1 = hp2[(size_t)s1 * 64 + lane];
        float2 v2 = hp2[(size_t)s2 * 64 + lane];
        float2 v3 = hp2[(size_t)s3 * 64 + lane];
        acc.x += v0.x + v1.x + v2.x + v3.x;
        acc.y += v0.y + v1.y + v2.y + v3.y;
    }
    for (; e < end; ++e) {
        int s = src[e];
        float2 v = hp2[(size_t)s * 64 + lane];
        acc.x += v.x; acc.y += v.y;
    }
    float di = dinv[wid];
    float2 b = ((const float2*)bias)[lane];
    float2 o;
    o.x = fmaxf(fmaf(di, acc.x, b.x), 0.f);
    o.y = fmaxf(fmaf(di, acc.y, b.y), 0.f);
    ((float2*)out)[(size_t)wid * 64 + lane] = o;
}

// ---------------------------------------------------------------- pool init + segment max
__global__ __launch_bounds__(128) void k_pool_init(int* __restrict__ pool) {
    pool[blockIdx.x * 128 + threadIdx.x] = 0;
}

__global__ __launch_bounds__(128) void k_pool(const float* __restrict__ h, const int* __restrict__ batch,
                                              int* __restrict__ pool, int n) {
    int c = threadIdx.x;
    int nb = gridDim.x;
    int chunk = (n + nb - 1) / nb;
    int beg = blockIdx.x * chunk;
    int end = min(beg + chunk, n);
    if (beg >= end) return;
    int g = batch[beg];
    float m = h[(size_t)beg * D + c];
    for (int i = beg + 1; i < end; ++i) {
        int gi = batch[i];
        float v = h[(size_t)i * D + c];
        if (gi != g) {
            atomicMax(&pool[g * D + c], __float_as_int(m));  // relu output >= 0 -> int cmp valid
            g = gi; m = v;
        } else {
            m = fmaxf(m, v);
        }
    }
    atomicMax(&pool[g * D + c], __float_as_int(m));
}

// ---------------------------------------------------------------- final MLP + log_softmax, 1 block/graph
__global__ __launch_bounds__(128) void k_mlp(const float* __restrict__ pool, const float* __restrict__ W0,
                                             const float* __restrict__ b0, const float* __restrict__ W1,
                                             const float* __restrict__ b1, float* __restrict__ out) {
    __shared__ float rowv[128];
    __shared__ float h2[128];
    __shared__ float h3[10];
    int g = blockIdx.x, t = threadIdx.x;
    rowv[t] = pool[g * 128 + t];
    __syncthreads();
    float acc = b0[t];
    for (int k = 0; k < 128; ++k) acc = fmaf(rowv[k], W0[k * 128 + t], acc);
    h2[t] = fmaxf(acc, 0.f);
    __syncthreads();
    if (t < 10) {
        float a = b1[t];
        for (int k = 0; k < 128; ++k) a = fmaf(h2[k], W1[k * 10 + t], a);
        h3[t] = fmaxf(a, 0.f);
    }
    __syncthreads();
    if (t == 0) {
        float mx = h3[0];
        for (int j = 1; j < 10; ++j) mx = fmaxf(mx, h3[j]);
        float s = 0.f;
        for (int j = 0; j < 10; ++j) s += expf(h3[j] - mx);
        float lse = logf(s) + mx;
        for (int j = 0; j < 10; ++j) out[g * 10 + j] = h3[j] - lse;
    }
}

// ----------------------------------------------------------------
extern "C" void kernel_launch(void* const* d_in, const int* in_sizes, int n_in,
                              void* d_out, int out_size, void* d_ws, size_t ws_size,
                              hipStream_t stream) {
    const float* x   = (const float*)d_in[0];
    const int* eidx  = (const int*)d_in[1];
    const int* batch = (const int*)d_in[2];
    const float* w0  = (const float*)d_in[3];
    const float* b0  = (const float*)d_in[4];
    const float* w1  = (const float*)d_in[5];
    const float* b1  = (const float*)d_in[6];
    const float* lw0 = (const float*)d_in[7];
    const float* lb0 = (const float*)d_in[8];
    const float* lw1 = (const float*)d_in[9];
    const float* lb1 = (const float*)d_in[10];
    float* out = (float*)d_out;

    int n = in_sizes[2];
    int E = in_sizes[1] / 2;
    const int* row = eidx;        // sources
    const int* col = eidx + E;    // destinations

    char* ws = (char*)d_ws;
    size_t o = 0;
    auto take = [&](size_t bytes) { void* p = ws + o; o += (bytes + 255) & ~(size_t)255; return p; };
    int*   deg     = (int*)  take((size_t)n * 4);
    int*   offsets = (int*)  take((size_t)(n + 1) * 4);
    int*   cursor  = (int*)  take((size_t)n * 4);
    int*   csr     = (int*)  take((size_t)E * 4);
    float* dinv    = (float*)take((size_t)n * 4);
    float* bufA    = (float*)take((size_t)n * D * 4);
    float* bufB    = (float*)take((size_t)n * D * 4);
    float* pool    = (float*)take(64 * D * 4);

    k_deg_init<<<(n + 255) / 256, 256, 0, stream>>>(deg, n);
    k_count<<<(E + 255) / 256, 256, 0, stream>>>(col, deg, E);
    k_scan<<<1, 1024, 0, stream>>>(deg, offsets, cursor, dinv, n);
    k_fill<<<(E + 255) / 256, 256, 0, stream>>>(row, col, cursor, csr, E);

    // conv0: h' = dinv * (x @ W0); agg -> relu
    k_gemm<<<(n + 63) / 64, 256, 0, stream>>>(x, w0, dinv, bufA, n);
    k_agg<<<(n + 3) / 4, 256, 0, stream>>>(bufA, offsets, csr, dinv, b0, bufB, n);
    // conv1
    k_gemm<<<(n + 63) / 64, 256, 0, stream>>>(bufB, w1, dinv, bufA, n);
    k_agg<<<(n + 3) / 4, 256, 0, stream>>>(bufA, offsets, csr, dinv, b1, bufB, n);

    k_pool_init<<<64, 128, 0, stream>>>((int*)pool);
    k_pool<<<512, 128, 0, stream>>>(bufB, batch, (int*)pool, n);
    k_mlp<<<64, 128, 0, stream>>>(pool, lw0, lb0, lw1, lb1, out);
}

// Round 2
// 439.527 us; speedup vs baseline: 1.2798x; 1.2798x over previous
//
#include <hip/hip_runtime.h>

#define D 128
#define TILE 256

// ---------------------------------------------------------------- degree init
__global__ __launch_bounds__(256) void k_deg_init(int* __restrict__ deg, int n) {
    int i = blockIdx.x * 256 + threadIdx.x;
    if (i < n) deg[i] = 1;  // self-loop
}

// ---------------------------------------------------------------- degree count
__global__ __launch_bounds__(256) void k_count(const int* __restrict__ col, int* __restrict__ deg, int E) {
    int e = blockIdx.x * 256 + threadIdx.x;
    if (e < E) atomicAdd(&deg[col[e]], 1);
}

// ---------------------------------------------------------------- scan phase 1: per-tile sum of (deg-1)
__global__ __launch_bounds__(TILE) void k_tilesum(const int* __restrict__ deg, int* __restrict__ tileSum, int n) {
    __shared__ int s[TILE];
    int t = threadIdx.x;
    int i = blockIdx.x * TILE + t;
    s[t] = (i < n) ? deg[i] - 1 : 0;
    __syncthreads();
    for (int off = TILE / 2; off > 0; off >>= 1) {
        if (t < off) s[t] += s[t + off];
        __syncthreads();
    }
    if (t == 0) tileSum[blockIdx.x] = s[0];
}

// ---------------------------------------------------------------- scan phase 2: scan tile sums (1 block)
__global__ __launch_bounds__(TILE) void k_tilescan(const int* __restrict__ tileSum, int* __restrict__ tileBase,
                                                   int* __restrict__ total_out, int nTiles) {
    __shared__ int s[TILE];
    int t = threadIdx.x;
    int v = (t < nTiles) ? tileSum[t] : 0;
    s[t] = v;
    __syncthreads();
    for (int off = 1; off < TILE; off <<= 1) {
        int tmp = (t >= off) ? s[t - off] : 0;
        __syncthreads();
        s[t] += tmp;
        __syncthreads();
    }
    if (t < nTiles) tileBase[t] = s[t] - v;       // exclusive base per tile
    if (t == TILE - 1) total_out[0] = s[TILE - 1]; // offsets[n] = E
}

// ---------------------------------------------------------------- scan phase 3: in-tile scan -> offsets/cursor/dinv
__global__ __launch_bounds__(TILE) void k_offsets(const int* __restrict__ deg, const int* __restrict__ tileBase,
                                                  int* __restrict__ offsets, int* __restrict__ cursor,
                                                  float* __restrict__ dinv, int n) {
    __shared__ int s[TILE];
    int t = threadIdx.x;
    int i = blockIdx.x * TILE + t;
    int dg = (i < n) ? deg[i] : 1;
    int v = dg - 1;
    s[t] = v;
    __syncthreads();
    for (int off = 1; off < TILE; off <<= 1) {
        int tmp = (t >= off) ? s[t - off] : 0;
        __syncthreads();
        s[t] += tmp;
        __syncthreads();
    }
    if (i < n) {
        int excl = s[t] - v + tileBase[blockIdx.x];
        offsets[i] = excl;
        cursor[i] = excl;
        dinv[i] = rsqrtf((float)dg);
    }
}

// ---------------------------------------------------------------- CSR fill (counting sort by dst)
__global__ __launch_bounds__(256) void k_fill(const int* __restrict__ row, const int* __restrict__ col,
                                              int* __restrict__ cursor, int* __restrict__ csr, int E) {
    int e = blockIdx.x * 256 + threadIdx.x;
    if (e < E) {
        int d = col[e];
        int p = atomicAdd(&cursor[d], 1);
        csr[p] = row[e];
    }
}

// ---------------------------------------------------------------- out[r,:] = dinv[r] * (in[r,:] @ W)
// 64 rows/block, 256 threads, thread = 8 rows x 4 cols microtile. W + x-tile in LDS.
__global__ __launch_bounds__(256) void k_gemm(const float* __restrict__ in, const float* __restrict__ W,
                                              const float* __restrict__ dinv, float* __restrict__ out, int n) {
    __shared__ float Ws[D * D];      // 64 KB
    __shared__ float Xs[64 * D];     // 32 KB
    int t = threadIdx.x;
    const float4* W4 = (const float4*)W;
    float4* Ws4 = (float4*)Ws;
#pragma unroll
    for (int i = 0; i < 16; ++i) Ws4[t + i * 256] = W4[t + i * 256];
    int row0 = blockIdx.x * 64;
    const float4* X4 = (const float4*)in;
    float4* Xs4 = (float4*)Xs;
#pragma unroll
    for (int i = 0; i < 8; ++i) {
        int idx = t + i * 256;                  // 0..2047
        int r = row0 + (idx >> 5);
        Xs4[idx] = (r < n) ? X4[(size_t)r * 32 + (idx & 31)] : make_float4(0.f, 0.f, 0.f, 0.f);
    }
    __syncthreads();
    int ty = t >> 5, tx = t & 31;
    int rbase = ty * 8;
    int c0 = tx * 4;
    float4 acc[8];
#pragma unroll
    for (int i = 0; i < 8; ++i) acc[i] = make_float4(0.f, 0.f, 0.f, 0.f);
    for (int k = 0; k < D; k += 4) {
        float4 w0 = *(const float4*)&Ws[(k + 0) * D + c0];
        float4 w1 = *(const float4*)&Ws[(k + 1) * D + c0];
        float4 w2 = *(const float4*)&Ws[(k + 2) * D + c0];
        float4 w3 = *(const float4*)&Ws[(k + 3) * D + c0];
#pragma unroll
        for (int i = 0; i < 8; ++i) {
            float4 xv = *(const float4*)&Xs[(rbase + i) * D + k];
            acc[i].x += xv.x * w0.x + xv.y * w1.x + xv.z * w2.x + xv.w * w3.x;
            acc[i].y += xv.x * w0.y + xv.y * w1.y + xv.z * w2.y + xv.w * w3.y;
            acc[i].z += xv.x * w0.z + xv.y * w1.z + xv.z * w2.z + xv.w * w3.z;
            acc[i].w += xv.x * w0.w + xv.y * w1.w + xv.z * w2.w + xv.w * w3.w;
        }
    }
#pragma unroll
    for (int i = 0; i < 8; ++i) {
        int r = row0 + rbase + i;
        if (r < n) {
            float s = dinv[r];
            float4 v = acc[i];
            v.x *= s; v.y *= s; v.z *= s; v.w *= s;
            *(float4*)&out[(size_t)r * D + c0] = v;
        }
    }
}

// ---------------------------------------------------------------- aggregation: one wave per node
// out[i,:] = relu(dinv[i]*(hp[i,:] + sum_{j in CSR[i]} hp[j,:]) + bias)
__global__ __launch_bounds__(256) void k_agg(const float* __restrict__ hp, const int* __restrict__ offs,
                                             const int* __restrict__ src, const float* __restrict__ dinv,
                                             const float* __restrict__ bias, float* __restrict__ out, int n) {
    int wid = (blockIdx.x * 256 + threadIdx.x) >> 6;
    int lane = threadIdx.x & 63;
    if (wid >= n) return;
    const float2* hp2 = (const float2*)hp;
    float2 acc = hp2[(size_t)wid * 64 + lane];   // self-loop contribution
    int beg = offs[wid], end = offs[wid + 1];
    int e = beg;
    for (; e + 4 <= end; e += 4) {
        int s0 = src[e], s1 = src[e + 1], s2 = src[e + 2], s3 = src[e + 3];
        float2 v0 = hp2[(size_t)s0 * 64 + lane];
        float2 v1 = hp2[(size_t)s1 * 64 + lane];
        float2 v2 = hp2[(size_t)s2 * 64 + lane];
        float2 v3 = hp2[(size_t)s3 * 64 + lane];
        acc.x += v0.x + v1.x + v2.x + v3.x;
        acc.y += v0.y + v1.y + v2.y + v3.y;
    }
    for (; e < end; ++e) {
        int s = src[e];
        float2 v = hp2[(size_t)s * 64 + lane];
        acc.x += v.x; acc.y += v.y;
    }
    float di = dinv[wid];
    float2 b = ((const float2*)bias)[lane];
    float2 o;
    o.x = fmaxf(fmaf(di, acc.x, b.x), 0.f);
    o.y = fmaxf(fmaf(di, acc.y, b.y), 0.f);
    ((float2*)out)[(size_t)wid * 64 + lane] = o;
}

// ---------------------------------------------------------------- pool init + segment max
__global__ __launch_bounds__(128) void k_pool_init(int* __restrict__ pool) {
    pool[blockIdx.x * 128 + threadIdx.x] = 0;
}

__global__ __launch_bounds__(128) void k_pool(const float* __restrict__ h, const int* __restrict__ batch,
                                              int* __restrict__ pool, int n) {
    int c = threadIdx.x;
    int nb = gridDim.x;
    int chunk = (n + nb - 1) / nb;
    int beg = blockIdx.x * chunk;
    int end = min(beg + chunk, n);
    if (beg >= end) return;
    int g = batch[beg];
    float m = h[(size_t)beg * D + c];
    for (int i = beg + 1; i < end; ++i) {
        int gi = batch[i];
        float v = h[(size_t)i * D + c];
        if (gi != g) {
            atomicMax(&pool[g * D + c], __float_as_int(m));  // relu output >= 0 -> int cmp valid
            g = gi; m = v;
        } else {
            m = fmaxf(m, v);
        }
    }
    atomicMax(&pool[g * D + c], __float_as_int(m));
}

// ---------------------------------------------------------------- final MLP + log_softmax, 1 block/graph
__global__ __launch_bounds__(128) void k_mlp(const float* __restrict__ pool, const float* __restrict__ W0,
                                             const float* __restrict__ b0, const float* __restrict__ W1,
                                             const float* __restrict__ b1, float* __restrict__ out) {
    __shared__ float rowv[128];
    __shared__ float h2[128];
    __shared__ float h3[10];
    int g = blockIdx.x, t = threadIdx.x;
    rowv[t] = pool[g * 128 + t];
    __syncthreads();
    float acc = b0[t];
    for (int k = 0; k < 128; ++k) acc = fmaf(rowv[k], W0[k * 128 + t], acc);
    h2[t] = fmaxf(acc, 0.f);
    __syncthreads();
    if (t < 10) {
        float a = b1[t];
        for (int k = 0; k < 128; ++k) a = fmaf(h2[k], W1[k * 10 + t], a);
        h3[t] = fmaxf(a, 0.f);
    }
    __syncthreads();
    if (t == 0) {
        float mx = h3[0];
        for (int j = 1; j < 10; ++j) mx = fmaxf(mx, h3[j]);
        float s = 0.f;
        for (int j = 0; j < 10; ++j) s += expf(h3[j] - mx);
        float lse = logf(s) + mx;
        for (int j = 0; j < 10; ++j) out[g * 10 + j] = h3[j] - lse;
    }
}

// ----------------------------------------------------------------
extern "C" void kernel_launch(void* const* d_in, const int* in_sizes, int n_in,
                              void* d_out, int out_size, void* d_ws, size_t ws_size,
                              hipStream_t stream) {
    const float* x   = (const float*)d_in[0];
    const int* eidx  = (const int*)d_in[1];
    const int* batch = (const int*)d_in[2];
    const float* w0  = (const float*)d_in[3];
    const float* b0  = (const float*)d_in[4];
    const float* w1  = (const float*)d_in[5];
    const float* b1  = (const float*)d_in[6];
    const float* lw0 = (const float*)d_in[7];
    const float* lb0 = (const float*)d_in[8];
    const float* lw1 = (const float*)d_in[9];
    const float* lb1 = (const float*)d_in[10];
    float* out = (float*)d_out;

    int n = in_sizes[2];
    int E = in_sizes[1] / 2;
    const int* row = eidx;        // sources
    const int* col = eidx + E;    // destinations
    int nTiles = (n + TILE - 1) / TILE;   // 196 for n=50000 (must be <= TILE)

    char* ws = (char*)d_ws;
    size_t o = 0;
    auto take = [&](size_t bytes) { void* p = ws + o; o += (bytes + 255) & ~(size_t)255; return p; };
    int*   deg      = (int*)  take((size_t)n * 4);
    int*   offsets  = (int*)  take((size_t)(n + 1) * 4);
    int*   cursor   = (int*)  take((size_t)n * 4);
    int*   csr      = (int*)  take((size_t)E * 4);
    float* dinv     = (float*)take((size_t)n * 4);
    int*   tileSum  = (int*)  take((size_t)nTiles * 4);
    int*   tileBase = (int*)  take((size_t)nTiles * 4);
    float* bufA     = (float*)take((size_t)n * D * 4);
    float* bufB     = (float*)take((size_t)n * D * 4);
    float* pool     = (float*)take(64 * D * 4);

    k_deg_init<<<(n + 255) / 256, 256, 0, stream>>>(deg, n);
    k_count<<<(E + 255) / 256, 256, 0, stream>>>(col, deg, E);
    k_tilesum<<<nTiles, TILE, 0, stream>>>(deg, tileSum, n);
    k_tilescan<<<1, TILE, 0, stream>>>(tileSum, tileBase, &offsets[n], nTiles);
    k_offsets<<<nTiles, TILE, 0, stream>>>(deg, tileBase, offsets, cursor, dinv, n);
    k_fill<<<(E + 255) / 256, 256, 0, stream>>>(row, col, cursor, csr, E);

    // conv0: h' = dinv * (x @ W0); agg -> relu
    k_gemm<<<(n + 63) / 64, 256, 0, stream>>>(x, w0, dinv, bufA, n);
    k_agg<<<(n + 3) / 4, 256, 0, stream>>>(bufA, offsets, csr, dinv, b0, bufB, n);
    // conv1
    k_gemm<<<(n + 63) / 64, 256, 0, stream>>>(bufB, w1, dinv, bufA, n);
    k_agg<<<(n + 3) / 4, 256, 0, stream>>>(bufA, offsets, csr, dinv, b1, bufB, n);

    k_pool_init<<<64, 128, 0, stream>>>((int*)pool);
    k_pool<<<512, 128, 0, stream>>>(bufB, batch, (int*)pool, n);
    k_mlp<<<64, 128, 0, stream>>>(pool, lw0, lb0, lw1, lb1, out);
}